// Round 4
// baseline (450.863 us; speedup 1.0000x reference)
//
#include <hip/hip_runtime.h>

// MS-SSIM loss, 5 levels, fused per-level kernel.
// Tile 64x16, 256 threads, LDS 34.3 KB -> 4 blocks/CU.
// h-fields ROW-MAJOR pitch 66 (r3: conflicts 2.4e7 -> 1.7e6, keep).
// R4 changes (kill divergent dual-path execution + hide load latency):
//  - pyramid levels 1-4 stored PADDED: 8 zero cols each side (stride W+16),
//    pointers pre-offset to logical col 0 -> every block pure float4 path.
//  - row-OOB handled by zero-page pointer select (conv is zero-padding).
//  - phase-H loads issued at kernel top; avg-pool runs while in flight.
//  - level 0 (unpadded input): only C0-edge blocks (2/8) take scalar path.

#define TW 64
#define TH 16
#define HHALO 26               // TH + 10
#define HPITCH 66              // even, not mult-of-4: 2-way banks (free)
#define PLANE (HHALO * HPITCH)
#define NIMG 48                // 16 * 3

__global__ __launch_bounds__(256, 4) void ssim_level_kernel(
    const float* __restrict__ x, const float* __restrict__ y,
    long imgStride, int rowStride,
    float* __restrict__ dsx, float* __restrict__ dsy,
    long dsImgStride, int dsRowStride,
    const float* __restrict__ zpad,
    float* __restrict__ sum_out, int H, int W, int pad, int do_ds)
{
    const float G[11] = {
        0.00102839f, 0.00759877f, 0.03600077f, 0.10936069f, 0.21300539f,
        0.26601173f, 0.21300539f, 0.10936069f, 0.03600077f, 0.00759877f,
        0.00102839f};
    const float C1 = 4.0e-4f;
    const float C2 = 3.6e-3f;

    __shared__ __align__(16) float hfT[5 * PLANE]; // 34,320 B
    __shared__ float wred[4];

    const int t   = threadIdx.x;
    const int img = blockIdx.z;
    const int C0  = blockIdx.x * TW;
    const int R0  = blockIdx.y * TH;
    const float* xi = x + (long)img * imgStride;
    const float* yi = y + (long)img * imgStride;

    // ---- strip setup + EARLY load issue (before avg-pool) ----
    const bool active = (t < HHALO * (TW / 8));   // 208 strips
    int r = 0, q = 0, gr = 0, gc0 = 0;
    bool rok = false, fastp = false;
    float4 ax[6], ay[6];
    if (active) {
        r   = t % HHALO;            // consecutive lanes -> consecutive rows
        q   = t / HHALO;
        gr  = R0 + r - 5;
        rok = ((unsigned)gr < (unsigned)H);
        gc0 = C0 + (q << 3) - 8;    // window start; taps use [gc0+3, gc0+21)
        fastp = pad || ((C0 >= 8) && (C0 + TW + 8 <= W));
        if (fastp) {
            const float* px = rok ? (xi + (long)gr * rowStride + gc0) : zpad;
            const float* py = rok ? (yi + (long)gr * rowStride + gc0) : zpad;
#pragma unroll
            for (int v = 0; v < 6; ++v) {
                ax[v] = reinterpret_cast<const float4*>(px)[v];
                ay[v] = reinterpret_cast<const float4*>(py)[v];
            }
        }
    }

    // ---- fused avg-pool 2x2 (overlaps the in-flight strip loads) ----
    if (do_ds) {
        const int dsW = W >> 1, dsH = H >> 1;
        const int dr = t >> 5, dc = t & 31;
        const int gr2 = (R0 >> 1) + dr;
        const int gc2 = (C0 >> 1) + dc;
        if (gr2 < dsH && gc2 < dsW) {
            const float* sx = xi + (long)(2 * gr2) * rowStride + 2 * gc2;
            const float* sy = yi + (long)(2 * gr2) * rowStride + 2 * gc2;
            const float2 a0 = *reinterpret_cast<const float2*>(sx);
            const float2 a1 = *reinterpret_cast<const float2*>(sx + rowStride);
            const float2 b0 = *reinterpret_cast<const float2*>(sy);
            const float2 b1 = *reinterpret_cast<const float2*>(sy + rowStride);
            const long o = (long)img * dsImgStride + (long)gr2 * dsRowStride + gc2;
            dsx[o] = 0.25f * (a0.x + a0.y + a1.x + a1.y);
            dsy[o] = 0.25f * (b0.x + b0.y + b1.x + b1.y);
        }
    }

    // ---- Phase H: horizontal conv of {x,y,xx,yy,xy}, 8 outputs/strip ----
    if (active) {
        float xv[24], yv[24];
        if (fastp) {
#pragma unroll
            for (int v = 0; v < 6; ++v) {
                xv[4 * v + 0] = ax[v].x; xv[4 * v + 1] = ax[v].y;
                xv[4 * v + 2] = ax[v].z; xv[4 * v + 3] = ax[v].w;
                yv[4 * v + 0] = ay[v].x; yv[4 * v + 1] = ay[v].y;
                yv[4 * v + 2] = ay[v].z; yv[4 * v + 3] = ay[v].w;
            }
        } else {
            const float* xrow = xi + (long)gr * rowStride;
            const float* yrow = yi + (long)gr * rowStride;
#pragma unroll
            for (int k = 3; k < 21; ++k) {
                const int gc = gc0 + k;
                const bool ok = rok && ((unsigned)gc < (unsigned)W);
                xv[k] = ok ? xrow[gc] : 0.0f;
                yv[k] = ok ? yrow[gc] : 0.0f;
            }
        }

        float xx[18], yy[18], xy[18];
#pragma unroll
        for (int k = 0; k < 18; ++k) {
            const float a = xv[k + 3], b = yv[k + 3];
            xx[k] = a * a; yy[k] = b * b; xy[k] = a * b;
        }

        float hx[8], hy[8], hxx[8], hyy[8], hxy[8];
#pragma unroll
        for (int j = 0; j < 8; ++j) {
            float sx = 0.f, sy = 0.f, sxx = 0.f, syy = 0.f, sxy = 0.f;
#pragma unroll
            for (int k = 0; k < 11; ++k) {
                const float g = G[k];
                sx  = fmaf(g, xv[j + k + 3], sx);
                sy  = fmaf(g, yv[j + k + 3], sy);
                sxx = fmaf(g, xx[j + k], sxx);
                syy = fmaf(g, yy[j + k], syy);
                sxy = fmaf(g, xy[j + k], sxy);
            }
            hx[j] = sx; hy[j] = sy; hxx[j] = sxx; hyy[j] = syy; hxy[j] = sxy;
        }
        float* hp = &hfT[r * HPITCH + (q << 3)];   // even word offset: b64 ok
#pragma unroll
        for (int p = 0; p < 4; ++p) {
            reinterpret_cast<float2*>(hp + 0 * PLANE)[p] = make_float2(hx[2*p],  hx[2*p+1]);
            reinterpret_cast<float2*>(hp + 1 * PLANE)[p] = make_float2(hy[2*p],  hy[2*p+1]);
            reinterpret_cast<float2*>(hp + 2 * PLANE)[p] = make_float2(hxx[2*p], hxx[2*p+1]);
            reinterpret_cast<float2*>(hp + 3 * PLANE)[p] = make_float2(hyy[2*p], hyy[2*p+1]);
            reinterpret_cast<float2*>(hp + 4 * PLANE)[p] = make_float2(hxy[2*p], hxy[2*p+1]);
        }
    }
    __syncthreads();

    // ---- Phase V: thread = (col, 4-row strip); scalar b32 column reads ----
    const int c   = t & 63;
    const int rr0 = (t >> 6) << 2;
    float acc[5][4];
#pragma unroll
    for (int f = 0; f < 5; ++f) {
        const float* hp = &hfT[f * PLANE + rr0 * HPITCH + c];
        float hv[14];
#pragma unroll
        for (int k = 0; k < 14; ++k) hv[k] = hp[k * HPITCH];
#pragma unroll
        for (int i = 0; i < 4; ++i) {
            float a = 0.f;
#pragma unroll
            for (int k = 0; k < 11; ++k) a = fmaf(G[k], hv[i + k], a);
            acc[f][i] = a;
        }
    }

    float local = 0.f;
    const int gc = C0 + c;
#pragma unroll
    for (int i = 0; i < 4; ++i) {
        const int gr2 = R0 + rr0 + i;
        if (gr2 < H && gc < W) {
            const float mu1 = acc[0][i], mu2 = acc[1][i];
            const float mu1s = mu1 * mu1, mu2s = mu2 * mu2, m12 = mu1 * mu2;
            const float s1  = acc[2][i] - mu1s;
            const float s2  = acc[3][i] - mu2s;
            const float s12 = acc[4][i] - m12;
            const float num = (2.f * m12 + C1) * (2.f * s12 + C2);
            const float den = (mu1s + mu2s + C1) * (s1 + s2 + C2);
            local += num * __builtin_amdgcn_rcpf(den + 1e-8f);
        }
    }

#pragma unroll
    for (int off = 32; off > 0; off >>= 1) local += __shfl_down(local, off, 64);
    if ((t & 63) == 0) wred[t >> 6] = local;
    __syncthreads();
    if (t == 0) atomicAdd(sum_out, wred[0] + wred[1] + wred[2] + wred[3]);
}

__global__ void finalize_kernel(const float* __restrict__ sums,
                                float* __restrict__ out)
{
    if (threadIdx.x == 0 && blockIdx.x == 0) {
        const float w[5] = {0.0448f, 0.2856f, 0.3001f, 0.2363f, 0.1333f};
        const float wsum = w[0] + w[1] + w[2] + w[3] + w[4];
        float acc = 0.f;
#pragma unroll
        for (int i = 0; i < 5; ++i) {
            const int d = 512 >> i;
            const float cnt = (float)NIMG * (float)d * (float)d;
            acc += (w[i] / wsum) * (sums[i] / cnt);
        }
        out[0] = 1.0f - acc;
    }
}

extern "C" void kernel_launch(void* const* d_in, const int* in_sizes, int n_in,
                              void* d_out, int out_size, void* d_ws, size_t ws_size,
                              hipStream_t stream)
{
    const float* pred = (const float*)d_in[0];
    const float* targ = (const float*)d_in[1];
    float* out = (float*)d_out;
    float* ws  = (float*)d_ws;

    // padded pyramid geometry: stride = W + 16 (8 zero cols each side)
    const long S1 = 256L * 272, S2 = 128L * 144, S3 = 64L * 80, S4 = 32L * 48;

    float* sums = ws;                       // 16 floats
    float* zpad = ws + 16;                  // 640 zero floats (row-OOB page)
    float* x1 = ws + 16 + 640;
    float* y1 = x1 + NIMG * S1;
    float* x2 = y1 + NIMG * S1;
    float* y2 = x2 + NIMG * S2;
    float* x3 = y2 + NIMG * S2;
    float* y3 = x3 + NIMG * S3;
    float* x4 = y3 + NIMG * S3;
    float* y4 = x4 + NIMG * S4;
    float* wsEnd = y4 + NIMG * S4 + 64;     // slack for level-4 tail overread

    // zero pads + zpad + sums in one shot (~36 MB, ~9 us)
    hipMemsetAsync(ws, 0, (size_t)(wsEnd - ws) * sizeof(float), stream);

    // level 0: unpadded harness input
    { dim3 g(8, 32, NIMG);
      ssim_level_kernel<<<g, 256, 0, stream>>>(pred, targ, 512L * 512, 512,
          x1 + 8, y1 + 8, S1, 272, zpad, sums + 0, 512, 512, 0, 1); }
    // level 1
    { dim3 g(4, 16, NIMG);
      ssim_level_kernel<<<g, 256, 0, stream>>>(x1 + 8, y1 + 8, S1, 272,
          x2 + 8, y2 + 8, S2, 144, zpad, sums + 1, 256, 256, 1, 1); }
    // level 2
    { dim3 g(2, 8, NIMG);
      ssim_level_kernel<<<g, 256, 0, stream>>>(x2 + 8, y2 + 8, S2, 144,
          x3 + 8, y3 + 8, S3, 80, zpad, sums + 2, 128, 128, 1, 1); }
    // level 3
    { dim3 g(1, 4, NIMG);
      ssim_level_kernel<<<g, 256, 0, stream>>>(x3 + 8, y3 + 8, S3, 80,
          x4 + 8, y4 + 8, S4, 48, zpad, sums + 3, 64, 64, 1, 1); }
    // level 4 (no downsample)
    { dim3 g(1, 2, NIMG);
      ssim_level_kernel<<<g, 256, 0, stream>>>(x4 + 8, y4 + 8, S4, 48,
          nullptr, nullptr, 0, 0, zpad, sums + 4, 32, 32, 1, 0); }

    finalize_kernel<<<1, 64, 0, stream>>>(sums, out);
}